// Round 14
// baseline (612.599 us; speedup 1.0000x reference)
//
#include <hip/hip_runtime.h>
#include <math.h>

#define N_NODES 50000
#define NPAD 50048       // N_NODES rounded up to 128 (GEMM tiles, no bounds masks)
#define N_EDGES 400000
#define N_GRAPHS 512
#define NEG_SLOPE 0.2f
#define BN_EPS 1e-5f
#define SCAN_BLOCKS 49   // ceil(50000/1024)
#define NBIN 256         // degree bins for counting sort

// leaky(z,0.2) = 0.6z + 0.4|z|; fold 1/ln2 so exp() becomes exp2()
#define C6 0.8656170245333781f   // 0.6 / ln2
#define C4 0.5770780163555854f   // 0.4 / ln2
#define THR_LOG2 11.541560327111708f  // 8 / ln2

typedef __attribute__((ext_vector_type(8))) short bf16x8;
typedef __attribute__((ext_vector_type(4))) float f32x4;

// ---- fp32 -> bf16 (round-to-nearest-even) ----
__device__ __forceinline__ ushort f2b(float f) {
    unsigned u = __float_as_uint(f);
    unsigned r = (u + 0x7fffu + ((u >> 16) & 1u)) >> 16;
    return (ushort)r;
}
__device__ __forceinline__ float b2f(ushort u) {
    return __uint_as_float((unsigned)u << 16);
}
// unpack a uint holding 2 bf16: element 0 = low half, element 1 = high half
__device__ __forceinline__ float b2f_lo(unsigned u) { return __uint_as_float(u << 16); }
__device__ __forceinline__ float b2f_hi(unsigned u) { return __uint_as_float(u & 0xffff0000u); }

// ---- async global->LDS, 16B per lane (dest = wave-uniform base + lane*16) ----
__device__ __forceinline__ void gld_lds16(const void* g, void* l) {
    __builtin_amdgcn_global_load_lds(
        (const __attribute__((address_space(1))) void*)g,
        (__attribute__((address_space(3))) void*)l, 16, 0, 0);
}

// ---- activation fp32 -> bf16, vectorized x4 ----
__global__ void cvt_kernel(const float* __restrict__ in, ushort* __restrict__ out,
                           int total4) {
    const int i = blockIdx.x * 256 + threadIdx.x;
    if (i >= total4) return;
    float4 v = *(const float4*)(in + (size_t)i * 4);
    ushort4 o;
    o.x = f2b(v.x); o.y = f2b(v.y); o.z = f2b(v.z); o.w = f2b(v.w);
    *(ushort4*)(out + (size_t)i * 4) = o;
}

// ---- fused weight convert+transpose for all 3 layers ----
__global__ void wcvt_all_kernel(const float* __restrict__ Wl1, const float* __restrict__ Wr1,
                                const float* __restrict__ Wl2, const float* __restrict__ Wr2,
                                const float* __restrict__ Wl3, const float* __restrict__ Wr3,
                                ushort* __restrict__ wt1, ushort* __restrict__ wt2,
                                ushort* __restrict__ wt3) {
    const int i = blockIdx.x * 256 + threadIdx.x;
    if (i < 32768) {
        const int m = i >> 7, k = i & 127;
        const float v = (m < 128) ? Wl1[k * 128 + m] : Wr1[k * 128 + (m - 128)];
        wt1[i] = f2b(v);
    } else if (i < 98304) {
        const int j = i - 32768;
        const int m = j >> 7, k = j & 127;
        const float v = (m < 256) ? Wl2[k * 256 + m] : Wr2[k * 256 + (m - 256)];
        wt2[j] = f2b(v);
    } else if (i < 163840) {
        const int j = i - 98304;
        const int m = j >> 8, k = j & 255;
        const float v = (m < 128) ? Wl3[k * 128 + m] : Wr3[k * 128 + (m - 128)];
        wt3[j] = f2b(v);
    }
}

// ---- bf16 MFMA GEMM -> unified bf16 output C[NPAD][M] (M = 2*FO: [xl|xr]) ----
// BM=BN=128, BK=32, 4 waves (64x64/wave). global_load_lds staging, XOR-swizzled LDS.
__global__ __launch_bounds__(256) void gemm_bf16_kernel(
    const ushort* __restrict__ A, const ushort* __restrict__ Bt,
    ushort* __restrict__ C, int K, int M) {
    __shared__ ushort As[4096];   // 8 KB: 128 rows x 32 shorts (64 B/row), swizzled
    __shared__ ushort Bs[4096];
    const int tid = threadIdx.x;
    const int row0 = blockIdx.x * 128;
    const int col0 = blockIdx.y * 128;
    const int w = tid >> 6, lane = tid & 63;
    const int wr = (w >> 1) * 64, wc = (w & 1) * 64;
    const int lr = lane & 15, kg = lane >> 4;

    char* as_b = (char*)As;
    char* bs_b = (char*)Bs;

    const int o0 = tid * 16;
    const int o1 = o0 + 4096;
    const int u0 = o0 ^ ((o0 >> 3) & 0x30);
    const int u1 = o1 ^ ((o1 >> 3) & 0x30);
    const int ar0 = u0 >> 6, ac0 = (u0 >> 4) & 3;
    const int ar1 = (u1 >> 6) & 127, ac1 = (u1 >> 4) & 3;

    const ushort* ga0 = A + (size_t)(row0 + ar0) * K + ac0 * 8;
    const ushort* ga1 = A + (size_t)(row0 + ar1) * K + ac1 * 8;
    const ushort* gb0 = Bt + (size_t)(col0 + ar0) * K + ac0 * 8;
    const ushort* gb1 = Bt + (size_t)(col0 + ar1) * K + ac1 * 8;

    char* da0 = as_b + w * 1024;
    char* da1 = as_b + 4096 + w * 1024;
    char* db0 = bs_b + w * 1024;
    char* db1 = bs_b + 4096 + w * 1024;

    const int sxor = ((lr >> 1) & 3) << 4;
    const int abase = (((wr + lr) * 64) + kg * 16) ^ sxor;
    const int bbase = (((wc + lr) * 64) + kg * 16) ^ sxor;

    f32x4 acc[4][4];
#pragma unroll
    for (int i = 0; i < 4; ++i)
#pragma unroll
        for (int j = 0; j < 4; ++j) acc[i][j] = (f32x4){0.f, 0.f, 0.f, 0.f};

    for (int k0 = 0; k0 < K; k0 += 32) {
        gld_lds16(ga0, da0);
        gld_lds16(ga1, da1);
        gld_lds16(gb0, db0);
        gld_lds16(gb1, db1);
        ga0 += 32; ga1 += 32; gb0 += 32; gb1 += 32;
        __syncthreads();
        bf16x8 af[4], bfr[4];
#pragma unroll
        for (int mi = 0; mi < 4; ++mi)
            af[mi] = *(const bf16x8*)(as_b + abase + mi * 1024);
#pragma unroll
        for (int ni = 0; ni < 4; ++ni)
            bfr[ni] = *(const bf16x8*)(bs_b + bbase + ni * 1024);
#pragma unroll
        for (int mi = 0; mi < 4; ++mi)
#pragma unroll
            for (int ni = 0; ni < 4; ++ni)
                acc[mi][ni] = __builtin_amdgcn_mfma_f32_16x16x32_bf16(
                    af[mi], bfr[ni], acc[mi][ni], 0, 0, 0);
        __syncthreads();
    }
#pragma unroll
    for (int mi = 0; mi < 4; ++mi)
#pragma unroll
        for (int ni = 0; ni < 4; ++ni)
#pragma unroll
            for (int j = 0; j < 4; ++j) {
                const int r = row0 + wr + mi * 16 + kg * 4 + j;   // < NPAD (padded)
                C[(size_t)r * M + col0 + wc + ni * 16 + lr] = f2b(acc[mi][ni][j]);
            }
}

// ---- CSR build ----
__global__ void deg_count_kernel(const int* __restrict__ ei, int* __restrict__ deg) {
    const int e = blockIdx.x * 256 + threadIdx.x;
    if (e < N_EDGES) atomicAdd(&deg[ei[N_EDGES + e]], 1);
}

__global__ __launch_bounds__(256) void scanA_kernel(const int* __restrict__ deg,
                                                    int* __restrict__ rowp,
                                                    int* __restrict__ bsum) {
    const int t = threadIdx.x, b = blockIdx.x;
    const int i0 = b * 1024 + t * 4;
    int4 d = make_int4(0, 0, 0, 0);
    if (i0 + 3 < N_NODES) d = *(const int4*)(deg + i0);
    else {
        if (i0 + 0 < N_NODES) d.x = deg[i0 + 0];
        if (i0 + 1 < N_NODES) d.y = deg[i0 + 1];
        if (i0 + 2 < N_NODES) d.z = deg[i0 + 2];
    }
    const int tsum = d.x + d.y + d.z + d.w;
    int inc = tsum;
    const int lane = t & 63, wave = t >> 6;
#pragma unroll
    for (int o = 1; o < 64; o <<= 1) {
        int v = __shfl_up(inc, o, 64);
        if (lane >= o) inc += v;
    }
    __shared__ int wsum[4];
    if (lane == 63) wsum[wave] = inc;
    __syncthreads();
    int wbase = 0;
#pragma unroll
    for (int ww = 0; ww < 4; ++ww)
        if (ww < wave) wbase += wsum[ww];
    const int texcl = wbase + inc - tsum;
    int4 o4;
    o4.x = texcl;
    o4.y = o4.x + d.x;
    o4.z = o4.y + d.y;
    o4.w = o4.z + d.z;
    if (i0 + 3 < N_NODES) *(int4*)(rowp + i0) = o4;
    else {
        if (i0 + 0 < N_NODES) rowp[i0 + 0] = o4.x;
        if (i0 + 1 < N_NODES) rowp[i0 + 1] = o4.y;
        if (i0 + 2 < N_NODES) rowp[i0 + 2] = o4.z;
    }
    if (t == 255) bsum[b] = wbase + inc;
}

__global__ __launch_bounds__(256) void scanC_kernel(const int* __restrict__ bsum,
                                                    int* __restrict__ rowp) {
    const int t = threadIdx.x, b = blockIdx.x;
    __shared__ int base_s;
    if (t < 64) {
        int v = (t < b) ? bsum[t] : 0;
#pragma unroll
        for (int o = 32; o; o >>= 1) v += __shfl_xor(v, o, 64);
        if (t == 0) base_s = v;
    }
    __syncthreads();
    const int base = base_s;
    const int i0 = b * 1024 + t * 4;
    if (base != 0) {
        if (i0 + 3 < N_NODES) {
            int4 v = *(int4*)(rowp + i0);
            v.x += base; v.y += base; v.z += base; v.w += base;
            *(int4*)(rowp + i0) = v;
        } else {
            if (i0 + 0 < N_NODES) rowp[i0 + 0] += base;
            if (i0 + 1 < N_NODES) rowp[i0 + 1] += base;
            if (i0 + 2 < N_NODES) rowp[i0 + 2] += base;
        }
    }
    if (b == 0 && t == 0) rowp[N_NODES] = N_EDGES;
}

__global__ void csr_fill_kernel(const int* __restrict__ ei, const int* __restrict__ rowp,
                                int* __restrict__ cursor, int* __restrict__ csr_src) {
    const int e = blockIdx.x * 256 + threadIdx.x;
    if (e >= N_EDGES) return;
    const int d = ei[N_EDGES + e];
    const int pos = atomicAdd(&cursor[d], 1);
    csr_src[rowp[d] + pos] = ei[e];
}

// ---- degree counting sort (descending): histogram -> scan -> scatter ----
__global__ void dhist_kernel(const int* __restrict__ deg, int* __restrict__ hist) {
    const int i = blockIdx.x * 256 + threadIdx.x;
    if (i < N_NODES) atomicAdd(&hist[min(deg[i], NBIN - 1)], 1);
}

// base[b] = sum of hist[b'] for b' > b  (descending-degree layout)
__global__ __launch_bounds__(NBIN) void dscan_kernel(const int* __restrict__ hist,
                                                     int* __restrict__ base) {
    __shared__ int h[NBIN];
    const int t = threadIdx.x;
    h[t] = hist[t];
    __syncthreads();
    int s = 0;
    for (int b = t + 1; b < NBIN; ++b) s += h[b];
    base[t] = s;
}

__global__ void dperm_kernel(const int* __restrict__ deg, const int* __restrict__ base,
                             int* __restrict__ bcur, int* __restrict__ perm) {
    const int i = blockIdx.x * 256 + threadIdx.x;
    if (i >= N_NODES) return;
    const int b = min(deg[i], NBIN - 1);
    const int pos = atomicAdd(&bcur[b], 1);
    perm[base[b] + pos] = i;
}

// ---- online-softmax stream update, log2 domain, defer-max (static indexing only) ----
template <int VEC>
__device__ __forceinline__ void sm_upd(float& m, float& s, float* acc, float p,
                                       const float* l) {
    if (p > m + THR_LOG2) {          // half-wave-uniform; rare after warmup (defer-max)
        const float sc = __builtin_amdgcn_exp2f(m - p);  // exp2(-inf)=0: first edge ok
        s = s * sc + 1.f;
#pragma unroll
        for (int k = 0; k < VEC; ++k) acc[k] = acc[k] * sc + l[k];
        m = p;
    } else {
        const float w = __builtin_amdgcn_exp2f(p - m);
        s += w;
#pragma unroll
        for (int k = 0; k < VEC; ++k) acc[k] += w * l[k];
    }
}

// ---- gather one src row (VEC bf16, half-wave layout) + att dot partial ----
template <int FO, int VEC>
__device__ __forceinline__ float edge_dot(const ushort* __restrict__ hx, int src, int co,
                                          const float* a6, const float* a4,
                                          const float* r, float* l) {
    if constexpr (VEC == 8) {
        uint4 t = *(const uint4*)(hx + (size_t)src * (2 * FO) + co);
        l[0] = b2f_lo(t.x); l[1] = b2f_hi(t.x);
        l[2] = b2f_lo(t.y); l[3] = b2f_hi(t.y);
        l[4] = b2f_lo(t.z); l[5] = b2f_hi(t.z);
        l[6] = b2f_lo(t.w); l[7] = b2f_hi(t.w);
    } else {
        uint2 t = *(const uint2*)(hx + (size_t)src * (2 * FO) + co);
        l[0] = b2f_lo(t.x); l[1] = b2f_hi(t.x);
        l[2] = b2f_lo(t.y); l[3] = b2f_hi(t.y);
    }
    float p = 0.f;
#pragma unroll
    for (int k = 0; k < VEC; ++k) {
        const float z = l[k] + r[k];
        p = fmaf(a6[k], z, p);
        p = fmaf(a4[k], fabsf(z), p);
    }
    return p;
}

// ---- fused GATv2 edge phase: TWO dsts per wave (half-wave each), 2-edge unroll,
// degree-sorted dst permutation (waves pair near-equal degrees), log2 softmax.
// hx: [NPAD][2*FO] bf16, xl=[0,FO), xr=[FO,2FO). VEC = FO/32.
template <int FO, int VEC>
__global__ __launch_bounds__(256) void gat_edge_kernel(
    const int* __restrict__ rowp, const int* __restrict__ csr_src,
    const int* __restrict__ perm, const ushort* __restrict__ hx,
    const float* __restrict__ att, const float* __restrict__ bias,
    float* __restrict__ outf, ushort* __restrict__ outb, int do_relu) {
    const int di = blockIdx.x * 8 + (threadIdx.x >> 5);
    const int lane = threadIdx.x & 31;
    if (di >= N_NODES) return;
    const int d = perm[di];
    const int co = lane * VEC;

    // a6 = 0.6*att/ln2, a4 = 0.4*att/ln2  (leaky(z)=0.6z+0.4|z|, exp->exp2)
    float a6[VEC], a4[VEC], r[VEC];
#pragma unroll
    for (int k = 0; k < VEC; ++k) {
        const float av = att[co + k];
        a6[k] = C6 * av;
        a4[k] = C4 * av;
        r[k] = b2f(hx[(size_t)d * (2 * FO) + FO + co + k]);
    }

    const int jb = rowp[d], je = rowp[d + 1];
    float m0 = -INFINITY, s0 = 0.f, m1 = -INFINITY, s1 = 0.f;
    float acc0[VEC] = {}, acc1[VEC] = {};

    int j = jb;
    for (; j + 1 < je; j += 2) {
        const int sA = csr_src[j + 0];
        const int sB = csr_src[j + 1];
        float lA[VEC], lB[VEC];
        float pA = edge_dot<FO, VEC>(hx, sA, co, a6, a4, r, lA);
        float pB = edge_dot<FO, VEC>(hx, sB, co, a6, a4, r, lB);
#pragma unroll
        for (int o = 16; o; o >>= 1) {
            pA += __shfl_xor(pA, o, 64);
            pB += __shfl_xor(pB, o, 64);
        }
        sm_upd<VEC>(m0, s0, acc0, pA, lA);
        sm_upd<VEC>(m1, s1, acc1, pB, lB);
    }
    if (j < je) {                       // tail (<=1): static stream 0
        const int sA = csr_src[j];
        float lA[VEC];
        float pA = edge_dot<FO, VEC>(hx, sA, co, a6, a4, r, lA);
#pragma unroll
        for (int o = 16; o; o >>= 1) pA += __shfl_xor(pA, o, 64);
        sm_upd<VEC>(m0, s0, acc0, pA, lA);
    }

    // merge the two streams (guard deg==0; empty stream contributes exp2(-inf)=0)
    float s, acc[VEC];
    if (je > jb) {
        const float M = fmaxf(m0, m1);
        const float sc0 = __builtin_amdgcn_exp2f(m0 - M);
        const float sc1 = __builtin_amdgcn_exp2f(m1 - M);
        s = s0 * sc0 + s1 * sc1;
#pragma unroll
        for (int k = 0; k < VEC; ++k) acc[k] = acc0[k] * sc0 + acc1[k] * sc1;
    } else {
        s = 0.f;
#pragma unroll
        for (int k = 0; k < VEC; ++k) acc[k] = 0.f;
    }

    const float inv = 1.f / (s + 1e-16f);
#pragma unroll
    for (int k = 0; k < VEC; ++k) {
        float v = acc[k] * inv + bias[co + k];
        if (do_relu) v = fmaxf(v, 0.f);
        acc[k] = v;
    }
    if (outf) {
#pragma unroll
        for (int k = 0; k < VEC; k += 4)
            *(float4*)(outf + (size_t)d * FO + co + k) =
                make_float4(acc[k], acc[k + 1], acc[k + 2], acc[k + 3]);
    }
    if (outb) {
#pragma unroll
        for (int k = 0; k < VEC; k += 4) {
            ushort4 o;
            o.x = f2b(acc[k]); o.y = f2b(acc[k + 1]);
            o.z = f2b(acc[k + 2]); o.w = f2b(acc[k + 3]);
            *(ushort4*)(outb + (size_t)d * FO + co + k) = o;
        }
    }
}

// ---- graph boundaries from sorted batch ----
__global__ void gstart_kernel(const int* __restrict__ batch, int* __restrict__ gstart) {
    const int i = blockIdx.x * 256 + threadIdx.x;
    if (i >= N_NODES) return;
    const int b = batch[i];
    if (i == 0) {
        for (int g = 0; g <= b; ++g) gstart[g] = 0;
    } else {
        const int pb = batch[i - 1];
        for (int g = pb + 1; g <= b; ++g) gstart[g] = i;
    }
    if (i == N_NODES - 1) {
        for (int g = b + 1; g <= N_GRAPHS; ++g) gstart[g] = N_NODES;
    }
}

// ---- per-graph pool: one block per graph, zero atomics ----
__global__ __launch_bounds__(128) void pool2_kernel(const float* __restrict__ h,
                                                    const int* __restrict__ gstart,
                                                    float* __restrict__ gsum,
                                                    float* __restrict__ gcnt) {
    const int g = blockIdx.x, t = threadIdx.x;
    const int b = gstart[g], e = gstart[g + 1];
    float s = 0.f;
    for (int i = b; i < e; ++i) s += h[(size_t)i * 128 + t];
    gsum[g * 128 + t] = s;
    if (t == 0) gcnt[g] = (float)(e - b);
}

// ---- fused MLP head ----
__global__ __launch_bounds__(128) void mlp_kernel(
    const float* __restrict__ gsum, const float* __restrict__ gcnt,
    const float* __restrict__ W1, const float* __restrict__ b1,
    const float* __restrict__ W2, const float* __restrict__ b2,
    const float* __restrict__ W3, const float* __restrict__ b3,
    const float* __restrict__ bng_g, const float* __restrict__ bng_b,
    const float* __restrict__ bng_m, const float* __restrict__ bng_v,
    const float* __restrict__ bn1_g, const float* __restrict__ bn1_b,
    const float* __restrict__ bn1_m, const float* __restrict__ bn1_v,
    const float* __restrict__ bn2_g, const float* __restrict__ bn2_b,
    const float* __restrict__ bn2_m, const float* __restrict__ bn2_v,
    float* __restrict__ out) {
    __shared__ float s0[128], s1[128], s2[64];
    const int g = blockIdx.x, t = threadIdx.x;
    const float cnt = fmaxf(gcnt[g], 1.f);
    float v = gsum[g * 128 + t] / cnt;
    v = (v - bng_m[t]) * rsqrtf(bng_v[t] + BN_EPS) * bng_g[t] + bng_b[t];
    s0[t] = v;
    __syncthreads();
    float a1 = b1[t];
    for (int i = 0; i < 128; ++i) a1 += s0[i] * W1[i * 128 + t];
    a1 = fmaxf(a1, 0.f);
    a1 = (a1 - bn1_m[t]) * rsqrtf(bn1_v[t] + BN_EPS) * bn1_g[t] + bn1_b[t];
    s1[t] = a1;
    __syncthreads();
    if (t < 64) {
        float a2 = b2[t];
        for (int i = 0; i < 128; ++i) a2 += s1[i] * W2[i * 64 + t];
        a2 = fmaxf(a2, 0.f);
        a2 = (a2 - bn2_m[t]) * rsqrtf(bn2_v[t] + BN_EPS) * bn2_g[t] + bn2_b[t];
        s2[t] = a2;
    }
    __syncthreads();
    if (t < 2) {
        float a3 = b3[t];
        for (int i = 0; i < 64; ++i) a3 += s2[i] * W3[i * 2 + t];
        out[g * 2 + t] = fmaxf(a3, 0.f);
    }
}

extern "C" void kernel_launch(void* const* d_in, const int* in_sizes, int n_in,
                              void* d_out, int out_size, void* d_ws, size_t ws_size,
                              hipStream_t stream) {
    const float* x = (const float*)d_in[0];
    const int* ei = (const int*)d_in[1];
    const int* batch = (const int*)d_in[2];
    const float* Wl1 = (const float*)d_in[3];
    const float* Wr1 = (const float*)d_in[4];
    const float* att1 = (const float*)d_in[5];
    const float* b1 = (const float*)d_in[6];
    const float* Wl2 = (const float*)d_in[7];
    const float* Wr2 = (const float*)d_in[8];
    const float* att2 = (const float*)d_in[9];
    const float* b2 = (const float*)d_in[10];
    const float* Wl3 = (const float*)d_in[11];
    const float* Wr3 = (const float*)d_in[12];
    const float* att3 = (const float*)d_in[13];
    const float* b3 = (const float*)d_in[14];
    const float* Wlin1 = (const float*)d_in[15];
    const float* blin1 = (const float*)d_in[16];
    const float* Wlin2 = (const float*)d_in[17];
    const float* blin2 = (const float*)d_in[18];
    const float* Wlin3 = (const float*)d_in[19];
    const float* blin3 = (const float*)d_in[20];
    const float* bng_g = (const float*)d_in[21];
    const float* bng_b = (const float*)d_in[22];
    const float* bng_m = (const float*)d_in[23];
    const float* bng_v = (const float*)d_in[24];
    const float* bn1_g = (const float*)d_in[25];
    const float* bn1_b = (const float*)d_in[26];
    const float* bn1_m = (const float*)d_in[27];
    const float* bn1_v = (const float*)d_in[28];
    const float* bn2_g = (const float*)d_in[29];
    const float* bn2_b = (const float*)d_in[30];
    const float* bn2_m = (const float*)d_in[31];
    const float* bn2_v = (const float*)d_in[32];

    float* ws = (float*)d_ws;
    ushort* hx = (ushort*)ws;                            // unified [xl|xr] bf16 (NPAD*512)
    float* h3 = (float*)(hx + (size_t)NPAD * 512);       // fp32 L3 out (N*128)
    ushort* hbf = (ushort*)(h3 + (size_t)N_NODES * 128); // bf16 layer input (NPAD*256)
    ushort* wt1 = hbf + (size_t)NPAD * 256;              // 256*128
    ushort* wt2 = wt1 + 256 * 128;                       // 512*128
    ushort* wt3 = wt2 + 512 * 128;                       // 256*256
    int* deg = (int*)(wt3 + 256 * 256);                  // N
    int* cursor = deg + N_NODES;                         // N
    int* rowp = cursor + N_NODES;                        // N+1
    int* csr_src = rowp + N_NODES + 1;                   // E
    int* gstart = csr_src + N_EDGES;                     // G+1
    int* bsum = gstart + N_GRAPHS + 1;                   // SCAN_BLOCKS
    int* hist = bsum + SCAN_BLOCKS;                      // NBIN
    int* hbase = hist + NBIN;                            // NBIN
    int* bcur = hbase + NBIN;                            // NBIN
    int* perm = bcur + NBIN;                             // N
    float* gsum = (float*)(perm + N_NODES);              // G*128
    float* gcnt = gsum + (size_t)N_GRAPHS * 128;         // G

    const int eb = (N_EDGES + 255) / 256;
    const int nb256 = (N_NODES + 255) / 256;

    // ---- CSR build (hierarchical scan) + degree counting sort ----
    hipMemsetAsync(deg, 0, (size_t)N_NODES * 2 * 4, stream);  // deg + cursor
    hipMemsetAsync(hist, 0, (size_t)NBIN * 3 * 4, stream);    // hist + hbase + bcur
    deg_count_kernel<<<eb, 256, 0, stream>>>(ei, deg);
    scanA_kernel<<<SCAN_BLOCKS, 256, 0, stream>>>(deg, rowp, bsum);
    scanC_kernel<<<SCAN_BLOCKS, 256, 0, stream>>>(bsum, rowp);
    csr_fill_kernel<<<eb, 256, 0, stream>>>(ei, rowp, cursor, csr_src);
    dhist_kernel<<<nb256, 256, 0, stream>>>(deg, hist);
    dscan_kernel<<<1, NBIN, 0, stream>>>(hist, hbase);
    dperm_kernel<<<nb256, 256, 0, stream>>>(deg, hbase, bcur, perm);
    gstart_kernel<<<nb256, 256, 0, stream>>>(batch, gstart);

    // ---- weights + x -> bf16 ----
    wcvt_all_kernel<<<640, 256, 0, stream>>>(Wl1, Wr1, Wl2, Wr2, Wl3, Wr3, wt1, wt2, wt3);
    cvt_kernel<<<(N_NODES * 128 / 4 + 255) / 256, 256, 0, stream>>>(
        x, hbf, N_NODES * 128 / 4);

    const int nb = (N_NODES + 7) / 8;   // 8 dsts per 256-thread block
    const int gx = NPAD / 128;          // 391, no row guards (padded workspace rows)

    // L1: K=128, FO=128 (M=256)
    gemm_bf16_kernel<<<dim3(gx, 2), 256, 0, stream>>>(hbf, wt1, hx, 128, 256);
    gat_edge_kernel<128, 4><<<nb, 256, 0, stream>>>(rowp, csr_src, perm, hx,
                                                    att1, b1, nullptr, hbf, 1);
    // L2: K=128, FO=256 (M=512)
    gemm_bf16_kernel<<<dim3(gx, 4), 256, 0, stream>>>(hbf, wt2, hx, 128, 512);
    gat_edge_kernel<256, 8><<<nb, 256, 0, stream>>>(rowp, csr_src, perm, hx,
                                                    att2, b2, nullptr, hbf, 1);
    // L3: K=256, FO=128 (M=256) -> h3 fp32
    gemm_bf16_kernel<<<dim3(gx, 2), 256, 0, stream>>>(hbf, wt3, hx, 256, 256);
    gat_edge_kernel<128, 4><<<nb, 256, 0, stream>>>(rowp, csr_src, perm, hx,
                                                    att3, b3, h3, nullptr, 0);

    // pool (no atomics)
    pool2_kernel<<<N_GRAPHS, 128, 0, stream>>>(h3, gstart, gsum, gcnt);

    // MLP head
    mlp_kernel<<<N_GRAPHS, 128, 0, stream>>>(
        gsum, gcnt, Wlin1, blin1, Wlin2, blin2, Wlin3, blin3,
        bng_g, bng_b, bng_m, bng_v, bn1_g, bn1_b, bn1_m, bn1_v,
        bn2_g, bn2_b, bn2_m, bn2_v, (float*)d_out);
}

// Round 15
// 273.135 us; speedup vs baseline: 2.2428x; 2.2428x over previous
//
#include <hip/hip_runtime.h>
#include <math.h>

#define N_NODES 50000
#define NPAD 50048       // N_NODES rounded up to 128 (GEMM tiles, no bounds masks)
#define N_EDGES 400000
#define N_GRAPHS 512
#define NEG_SLOPE 0.2f
#define BN_EPS 1e-5f
#define SCAN_BLOCKS 49   // ceil(50000/1024)

// leaky(z,0.2) = 0.6z + 0.4|z|; fold 1/ln2 so exp() becomes exp2()
#define C6 0.8656170245333781f   // 0.6 / ln2
#define C4 0.5770780163555854f   // 0.4 / ln2
#define THR_LOG2 11.541560327111708f  // 8 / ln2

typedef __attribute__((ext_vector_type(8))) short bf16x8;
typedef __attribute__((ext_vector_type(4))) float f32x4;

// ---- fp32 -> bf16 (round-to-nearest-even) ----
__device__ __forceinline__ ushort f2b(float f) {
    unsigned u = __float_as_uint(f);
    unsigned r = (u + 0x7fffu + ((u >> 16) & 1u)) >> 16;
    return (ushort)r;
}
__device__ __forceinline__ float b2f(ushort u) {
    return __uint_as_float((unsigned)u << 16);
}
// unpack a uint holding 2 bf16: element 0 = low half, element 1 = high half
__device__ __forceinline__ float b2f_lo(unsigned u) { return __uint_as_float(u << 16); }
__device__ __forceinline__ float b2f_hi(unsigned u) { return __uint_as_float(u & 0xffff0000u); }

// ---- async global->LDS, 16B per lane (dest = wave-uniform base + lane*16) ----
__device__ __forceinline__ void gld_lds16(const void* g, void* l) {
    __builtin_amdgcn_global_load_lds(
        (const __attribute__((address_space(1))) void*)g,
        (__attribute__((address_space(3))) void*)l, 16, 0, 0);
}

// ---- activation fp32 -> bf16, vectorized x4 ----
__global__ void cvt_kernel(const float* __restrict__ in, ushort* __restrict__ out,
                           int total4) {
    const int i = blockIdx.x * 256 + threadIdx.x;
    if (i >= total4) return;
    float4 v = *(const float4*)(in + (size_t)i * 4);
    ushort4 o;
    o.x = f2b(v.x); o.y = f2b(v.y); o.z = f2b(v.z); o.w = f2b(v.w);
    *(ushort4*)(out + (size_t)i * 4) = o;
}

// ---- fused weight convert+transpose for all 3 layers ----
__global__ void wcvt_all_kernel(const float* __restrict__ Wl1, const float* __restrict__ Wr1,
                                const float* __restrict__ Wl2, const float* __restrict__ Wr2,
                                const float* __restrict__ Wl3, const float* __restrict__ Wr3,
                                ushort* __restrict__ wt1, ushort* __restrict__ wt2,
                                ushort* __restrict__ wt3) {
    const int i = blockIdx.x * 256 + threadIdx.x;
    if (i < 32768) {
        const int m = i >> 7, k = i & 127;
        const float v = (m < 128) ? Wl1[k * 128 + m] : Wr1[k * 128 + (m - 128)];
        wt1[i] = f2b(v);
    } else if (i < 98304) {
        const int j = i - 32768;
        const int m = j >> 7, k = j & 127;
        const float v = (m < 256) ? Wl2[k * 256 + m] : Wr2[k * 256 + (m - 256)];
        wt2[j] = f2b(v);
    } else if (i < 163840) {
        const int j = i - 98304;
        const int m = j >> 8, k = j & 255;
        const float v = (m < 128) ? Wl3[k * 128 + m] : Wr3[k * 128 + (m - 128)];
        wt3[j] = f2b(v);
    }
}

// ---- bf16 MFMA GEMM -> unified bf16 output C[NPAD][M] (M = 2*FO: [xl|xr]) ----
// BM=BN=128, BK=32, 4 waves (64x64/wave). global_load_lds staging, XOR-swizzled LDS.
__global__ __launch_bounds__(256) void gemm_bf16_kernel(
    const ushort* __restrict__ A, const ushort* __restrict__ Bt,
    ushort* __restrict__ C, int K, int M) {
    __shared__ ushort As[4096];   // 8 KB: 128 rows x 32 shorts (64 B/row), swizzled
    __shared__ ushort Bs[4096];
    const int tid = threadIdx.x;
    const int row0 = blockIdx.x * 128;
    const int col0 = blockIdx.y * 128;
    const int w = tid >> 6, lane = tid & 63;
    const int wr = (w >> 1) * 64, wc = (w & 1) * 64;
    const int lr = lane & 15, kg = lane >> 4;

    char* as_b = (char*)As;
    char* bs_b = (char*)Bs;

    const int o0 = tid * 16;
    const int o1 = o0 + 4096;
    const int u0 = o0 ^ ((o0 >> 3) & 0x30);
    const int u1 = o1 ^ ((o1 >> 3) & 0x30);
    const int ar0 = u0 >> 6, ac0 = (u0 >> 4) & 3;
    const int ar1 = (u1 >> 6) & 127, ac1 = (u1 >> 4) & 3;

    const ushort* ga0 = A + (size_t)(row0 + ar0) * K + ac0 * 8;
    const ushort* ga1 = A + (size_t)(row0 + ar1) * K + ac1 * 8;
    const ushort* gb0 = Bt + (size_t)(col0 + ar0) * K + ac0 * 8;
    const ushort* gb1 = Bt + (size_t)(col0 + ar1) * K + ac1 * 8;

    char* da0 = as_b + w * 1024;
    char* da1 = as_b + 4096 + w * 1024;
    char* db0 = bs_b + w * 1024;
    char* db1 = bs_b + 4096 + w * 1024;

    const int sxor = ((lr >> 1) & 3) << 4;
    const int abase = (((wr + lr) * 64) + kg * 16) ^ sxor;
    const int bbase = (((wc + lr) * 64) + kg * 16) ^ sxor;

    f32x4 acc[4][4];
#pragma unroll
    for (int i = 0; i < 4; ++i)
#pragma unroll
        for (int j = 0; j < 4; ++j) acc[i][j] = (f32x4){0.f, 0.f, 0.f, 0.f};

    for (int k0 = 0; k0 < K; k0 += 32) {
        gld_lds16(ga0, da0);
        gld_lds16(ga1, da1);
        gld_lds16(gb0, db0);
        gld_lds16(gb1, db1);
        ga0 += 32; ga1 += 32; gb0 += 32; gb1 += 32;
        __syncthreads();
        bf16x8 af[4], bfr[4];
#pragma unroll
        for (int mi = 0; mi < 4; ++mi)
            af[mi] = *(const bf16x8*)(as_b + abase + mi * 1024);
#pragma unroll
        for (int ni = 0; ni < 4; ++ni)
            bfr[ni] = *(const bf16x8*)(bs_b + bbase + ni * 1024);
#pragma unroll
        for (int mi = 0; mi < 4; ++mi)
#pragma unroll
            for (int ni = 0; ni < 4; ++ni)
                acc[mi][ni] = __builtin_amdgcn_mfma_f32_16x16x32_bf16(
                    af[mi], bfr[ni], acc[mi][ni], 0, 0, 0);
        __syncthreads();
    }
#pragma unroll
    for (int mi = 0; mi < 4; ++mi)
#pragma unroll
        for (int ni = 0; ni < 4; ++ni)
#pragma unroll
            for (int j = 0; j < 4; ++j) {
                const int r = row0 + wr + mi * 16 + kg * 4 + j;   // < NPAD (padded)
                C[(size_t)r * M + col0 + wc + ni * 16 + lr] = f2b(acc[mi][ni][j]);
            }
}

// ---- CSR build ----
__global__ void deg_count_kernel(const int* __restrict__ ei, int* __restrict__ deg) {
    const int e = blockIdx.x * 256 + threadIdx.x;
    if (e < N_EDGES) atomicAdd(&deg[ei[N_EDGES + e]], 1);
}

__global__ __launch_bounds__(256) void scanA_kernel(const int* __restrict__ deg,
                                                    int* __restrict__ rowp,
                                                    int* __restrict__ bsum) {
    const int t = threadIdx.x, b = blockIdx.x;
    const int i0 = b * 1024 + t * 4;
    int4 d = make_int4(0, 0, 0, 0);
    if (i0 + 3 < N_NODES) d = *(const int4*)(deg + i0);
    else {
        if (i0 + 0 < N_NODES) d.x = deg[i0 + 0];
        if (i0 + 1 < N_NODES) d.y = deg[i0 + 1];
        if (i0 + 2 < N_NODES) d.z = deg[i0 + 2];
    }
    const int tsum = d.x + d.y + d.z + d.w;
    int inc = tsum;
    const int lane = t & 63, wave = t >> 6;
#pragma unroll
    for (int o = 1; o < 64; o <<= 1) {
        int v = __shfl_up(inc, o, 64);
        if (lane >= o) inc += v;
    }
    __shared__ int wsum[4];
    if (lane == 63) wsum[wave] = inc;
    __syncthreads();
    int wbase = 0;
#pragma unroll
    for (int ww = 0; ww < 4; ++ww)
        if (ww < wave) wbase += wsum[ww];
    const int texcl = wbase + inc - tsum;
    int4 o4;
    o4.x = texcl;
    o4.y = o4.x + d.x;
    o4.z = o4.y + d.y;
    o4.w = o4.z + d.z;
    if (i0 + 3 < N_NODES) *(int4*)(rowp + i0) = o4;
    else {
        if (i0 + 0 < N_NODES) rowp[i0 + 0] = o4.x;
        if (i0 + 1 < N_NODES) rowp[i0 + 1] = o4.y;
        if (i0 + 2 < N_NODES) rowp[i0 + 2] = o4.z;
    }
    if (t == 255) bsum[b] = wbase + inc;
}

__global__ __launch_bounds__(256) void scanC_kernel(const int* __restrict__ bsum,
                                                    int* __restrict__ rowp) {
    const int t = threadIdx.x, b = blockIdx.x;
    __shared__ int base_s;
    if (t < 64) {
        int v = (t < b) ? bsum[t] : 0;
#pragma unroll
        for (int o = 32; o; o >>= 1) v += __shfl_xor(v, o, 64);
        if (t == 0) base_s = v;
    }
    __syncthreads();
    const int base = base_s;
    const int i0 = b * 1024 + t * 4;
    if (base != 0) {
        if (i0 + 3 < N_NODES) {
            int4 v = *(int4*)(rowp + i0);
            v.x += base; v.y += base; v.z += base; v.w += base;
            *(int4*)(rowp + i0) = v;
        } else {
            if (i0 + 0 < N_NODES) rowp[i0 + 0] += base;
            if (i0 + 1 < N_NODES) rowp[i0 + 1] += base;
            if (i0 + 2 < N_NODES) rowp[i0 + 2] += base;
        }
    }
    if (b == 0 && t == 0) rowp[N_NODES] = N_EDGES;
}

__global__ void csr_fill_kernel(const int* __restrict__ ei, const int* __restrict__ rowp,
                                int* __restrict__ cursor, int* __restrict__ csr_src) {
    const int e = blockIdx.x * 256 + threadIdx.x;
    if (e >= N_EDGES) return;
    const int d = ei[N_EDGES + e];
    const int pos = atomicAdd(&cursor[d], 1);
    csr_src[rowp[d] + pos] = ei[e];
}

// ---- online-softmax stream update, log2 domain, defer-max (static indexing only) ----
template <int VEC>
__device__ __forceinline__ void sm_upd(float& m, float& s, float* acc, float p,
                                       const float* l) {
    if (p > m + THR_LOG2) {          // half-wave-uniform; rare after warmup (defer-max)
        const float sc = __builtin_amdgcn_exp2f(m - p);  // exp2(-inf)=0: first edge ok
        s = s * sc + 1.f;
#pragma unroll
        for (int k = 0; k < VEC; ++k) acc[k] = acc[k] * sc + l[k];
        m = p;
    } else {
        const float w = __builtin_amdgcn_exp2f(p - m);
        s += w;
#pragma unroll
        for (int k = 0; k < VEC; ++k) acc[k] += w * l[k];
    }
}

// ---- gather one src row (VEC bf16, half-wave layout) + att dot partial ----
template <int FO, int VEC>
__device__ __forceinline__ float edge_dot(const ushort* __restrict__ hx, int src, int co,
                                          const float* a6, const float* a4,
                                          const float* r, float* l) {
    if constexpr (VEC == 8) {
        uint4 t = *(const uint4*)(hx + (size_t)src * (2 * FO) + co);
        l[0] = b2f_lo(t.x); l[1] = b2f_hi(t.x);
        l[2] = b2f_lo(t.y); l[3] = b2f_hi(t.y);
        l[4] = b2f_lo(t.z); l[5] = b2f_hi(t.z);
        l[6] = b2f_lo(t.w); l[7] = b2f_hi(t.w);
    } else {
        uint2 t = *(const uint2*)(hx + (size_t)src * (2 * FO) + co);
        l[0] = b2f_lo(t.x); l[1] = b2f_hi(t.x);
        l[2] = b2f_lo(t.y); l[3] = b2f_hi(t.y);
    }
    float p = 0.f;
#pragma unroll
    for (int k = 0; k < VEC; ++k) {
        const float z = l[k] + r[k];
        p = fmaf(a6[k], z, p);
        p = fmaf(a4[k], fabsf(z), p);
    }
    return p;
}

// ---- fused GATv2 edge phase: TWO dsts per wave (half-wave each), 2-edge unroll,
// log2-domain online softmax. hx: [NPAD][2*FO] bf16, xl=[0,FO), xr=[FO,2FO).
// VEC = FO/32. 256 threads = 8 dsts per block. Shuffle masks <=16 stay in-half.
template <int FO, int VEC>
__global__ __launch_bounds__(256) void gat_edge_kernel(
    const int* __restrict__ rowp, const int* __restrict__ csr_src,
    const ushort* __restrict__ hx,
    const float* __restrict__ att, const float* __restrict__ bias,
    float* __restrict__ outf, ushort* __restrict__ outb, int do_relu) {
    const int d = blockIdx.x * 8 + (threadIdx.x >> 5);
    const int lane = threadIdx.x & 31;
    if (d >= N_NODES) return;
    const int co = lane * VEC;

    // a6 = 0.6*att/ln2, a4 = 0.4*att/ln2  (leaky(z)=0.6z+0.4|z|, exp->exp2)
    float a6[VEC], a4[VEC], r[VEC];
#pragma unroll
    for (int k = 0; k < VEC; ++k) {
        const float av = att[co + k];
        a6[k] = C6 * av;
        a4[k] = C4 * av;
        r[k] = b2f(hx[(size_t)d * (2 * FO) + FO + co + k]);
    }

    const int jb = rowp[d], je = rowp[d + 1];
    float m0 = -INFINITY, s0 = 0.f, m1 = -INFINITY, s1 = 0.f;
    float acc0[VEC] = {}, acc1[VEC] = {};

    int j = jb;
    for (; j + 1 < je; j += 2) {
        const int sA = csr_src[j + 0];
        const int sB = csr_src[j + 1];
        float lA[VEC], lB[VEC];
        float pA = edge_dot<FO, VEC>(hx, sA, co, a6, a4, r, lA);
        float pB = edge_dot<FO, VEC>(hx, sB, co, a6, a4, r, lB);
#pragma unroll
        for (int o = 16; o; o >>= 1) {
            pA += __shfl_xor(pA, o, 64);
            pB += __shfl_xor(pB, o, 64);
        }
        sm_upd<VEC>(m0, s0, acc0, pA, lA);
        sm_upd<VEC>(m1, s1, acc1, pB, lB);
    }
    if (j < je) {                       // tail (<=1): static stream 0
        const int sA = csr_src[j];
        float lA[VEC];
        float pA = edge_dot<FO, VEC>(hx, sA, co, a6, a4, r, lA);
#pragma unroll
        for (int o = 16; o; o >>= 1) pA += __shfl_xor(pA, o, 64);
        sm_upd<VEC>(m0, s0, acc0, pA, lA);
    }

    // merge the two streams (guard deg==0; empty stream contributes exp2(-inf)=0)
    float s, acc[VEC];
    if (je > jb) {
        const float M = fmaxf(m0, m1);
        const float sc0 = __builtin_amdgcn_exp2f(m0 - M);
        const float sc1 = __builtin_amdgcn_exp2f(m1 - M);
        s = s0 * sc0 + s1 * sc1;
#pragma unroll
        for (int k = 0; k < VEC; ++k) acc[k] = acc0[k] * sc0 + acc1[k] * sc1;
    } else {
        s = 0.f;
#pragma unroll
        for (int k = 0; k < VEC; ++k) acc[k] = 0.f;
    }

    const float inv = 1.f / (s + 1e-16f);
#pragma unroll
    for (int k = 0; k < VEC; ++k) {
        float v = acc[k] * inv + bias[co + k];
        if (do_relu) v = fmaxf(v, 0.f);
        acc[k] = v;
    }
    if (outf) {
#pragma unroll
        for (int k = 0; k < VEC; k += 4)
            *(float4*)(outf + (size_t)d * FO + co + k) =
                make_float4(acc[k], acc[k + 1], acc[k + 2], acc[k + 3]);
    }
    if (outb) {
#pragma unroll
        for (int k = 0; k < VEC; k += 4) {
            ushort4 o;
            o.x = f2b(acc[k]); o.y = f2b(acc[k + 1]);
            o.z = f2b(acc[k + 2]); o.w = f2b(acc[k + 3]);
            *(ushort4*)(outb + (size_t)d * FO + co + k) = o;
        }
    }
}

// ---- graph boundaries from sorted batch ----
__global__ void gstart_kernel(const int* __restrict__ batch, int* __restrict__ gstart) {
    const int i = blockIdx.x * 256 + threadIdx.x;
    if (i >= N_NODES) return;
    const int b = batch[i];
    if (i == 0) {
        for (int g = 0; g <= b; ++g) gstart[g] = 0;
    } else {
        const int pb = batch[i - 1];
        for (int g = pb + 1; g <= b; ++g) gstart[g] = i;
    }
    if (i == N_NODES - 1) {
        for (int g = b + 1; g <= N_GRAPHS; ++g) gstart[g] = N_NODES;
    }
}

// ---- per-graph pool: one block per graph, zero atomics ----
__global__ __launch_bounds__(128) void pool2_kernel(const float* __restrict__ h,
                                                    const int* __restrict__ gstart,
                                                    float* __restrict__ gsum,
                                                    float* __restrict__ gcnt) {
    const int g = blockIdx.x, t = threadIdx.x;
    const int b = gstart[g], e = gstart[g + 1];
    float s = 0.f;
    for (int i = b; i < e; ++i) s += h[(size_t)i * 128 + t];
    gsum[g * 128 + t] = s;
    if (t == 0) gcnt[g] = (float)(e - b);
}

// ---- fused MLP head ----
__global__ __launch_bounds__(128) void mlp_kernel(
    const float* __restrict__ gsum, const float* __restrict__ gcnt,
    const float* __restrict__ W1, const float* __restrict__ b1,
    const float* __restrict__ W2, const float* __restrict__ b2,
    const float* __restrict__ W3, const float* __restrict__ b3,
    const float* __restrict__ bng_g, const float* __restrict__ bng_b,
    const float* __restrict__ bng_m, const float* __restrict__ bng_v,
    const float* __restrict__ bn1_g, const float* __restrict__ bn1_b,
    const float* __restrict__ bn1_m, const float* __restrict__ bn1_v,
    const float* __restrict__ bn2_g, const float* __restrict__ bn2_b,
    const float* __restrict__ bn2_m, const float* __restrict__ bn2_v,
    float* __restrict__ out) {
    __shared__ float s0[128], s1[128], s2[64];
    const int g = blockIdx.x, t = threadIdx.x;
    const float cnt = fmaxf(gcnt[g], 1.f);
    float v = gsum[g * 128 + t] / cnt;
    v = (v - bng_m[t]) * rsqrtf(bng_v[t] + BN_EPS) * bng_g[t] + bng_b[t];
    s0[t] = v;
    __syncthreads();
    float a1 = b1[t];
    for (int i = 0; i < 128; ++i) a1 += s0[i] * W1[i * 128 + t];
    a1 = fmaxf(a1, 0.f);
    a1 = (a1 - bn1_m[t]) * rsqrtf(bn1_v[t] + BN_EPS) * bn1_g[t] + bn1_b[t];
    s1[t] = a1;
    __syncthreads();
    if (t < 64) {
        float a2 = b2[t];
        for (int i = 0; i < 128; ++i) a2 += s1[i] * W2[i * 64 + t];
        a2 = fmaxf(a2, 0.f);
        a2 = (a2 - bn2_m[t]) * rsqrtf(bn2_v[t] + BN_EPS) * bn2_g[t] + bn2_b[t];
        s2[t] = a2;
    }
    __syncthreads();
    if (t < 2) {
        float a3 = b3[t];
        for (int i = 0; i < 64; ++i) a3 += s2[i] * W3[i * 2 + t];
        out[g * 2 + t] = fmaxf(a3, 0.f);
    }
}

extern "C" void kernel_launch(void* const* d_in, const int* in_sizes, int n_in,
                              void* d_out, int out_size, void* d_ws, size_t ws_size,
                              hipStream_t stream) {
    const float* x = (const float*)d_in[0];
    const int* ei = (const int*)d_in[1];
    const int* batch = (const int*)d_in[2];
    const float* Wl1 = (const float*)d_in[3];
    const float* Wr1 = (const float*)d_in[4];
    const float* att1 = (const float*)d_in[5];
    const float* b1 = (const float*)d_in[6];
    const float* Wl2 = (const float*)d_in[7];
    const float* Wr2 = (const float*)d_in[8];
    const float* att2 = (const float*)d_in[9];
    const float* b2 = (const float*)d_in[10];
    const float* Wl3 = (const float*)d_in[11];
    const float* Wr3 = (const float*)d_in[12];
    const float* att3 = (const float*)d_in[13];
    const float* b3 = (const float*)d_in[14];
    const float* Wlin1 = (const float*)d_in[15];
    const float* blin1 = (const float*)d_in[16];
    const float* Wlin2 = (const float*)d_in[17];
    const float* blin2 = (const float*)d_in[18];
    const float* Wlin3 = (const float*)d_in[19];
    const float* blin3 = (const float*)d_in[20];
    const float* bng_g = (const float*)d_in[21];
    const float* bng_b = (const float*)d_in[22];
    const float* bng_m = (const float*)d_in[23];
    const float* bng_v = (const float*)d_in[24];
    const float* bn1_g = (const float*)d_in[25];
    const float* bn1_b = (const float*)d_in[26];
    const float* bn1_m = (const float*)d_in[27];
    const float* bn1_v = (const float*)d_in[28];
    const float* bn2_g = (const float*)d_in[29];
    const float* bn2_b = (const float*)d_in[30];
    const float* bn2_m = (const float*)d_in[31];
    const float* bn2_v = (const float*)d_in[32];

    float* ws = (float*)d_ws;
    ushort* hx = (ushort*)ws;                            // unified [xl|xr] bf16 (NPAD*512)
    float* h3 = (float*)(hx + (size_t)NPAD * 512);       // fp32 L3 out (N*128)
    ushort* hbf = (ushort*)(h3 + (size_t)N_NODES * 128); // bf16 layer input (NPAD*256)
    ushort* wt1 = hbf + (size_t)NPAD * 256;              // 256*128
    ushort* wt2 = wt1 + 256 * 128;                       // 512*128
    ushort* wt3 = wt2 + 512 * 128;                       // 256*256
    int* deg = (int*)(wt3 + 256 * 256);                  // N
    int* cursor = deg + N_NODES;                         // N
    int* rowp = cursor + N_NODES;                        // N+1
    int* csr_src = rowp + N_NODES + 1;                   // E
    int* gstart = csr_src + N_EDGES;                     // G+1
    int* bsum = gstart + N_GRAPHS + 1;                   // SCAN_BLOCKS
    float* gsum = (float*)(bsum + SCAN_BLOCKS);          // G*128
    float* gcnt = gsum + (size_t)N_GRAPHS * 128;         // G

    const int eb = (N_EDGES + 255) / 256;

    // ---- CSR build (hierarchical scan) ----
    hipMemsetAsync(deg, 0, (size_t)N_NODES * 2 * 4, stream);  // deg + cursor
    deg_count_kernel<<<eb, 256, 0, stream>>>(ei, deg);
    scanA_kernel<<<SCAN_BLOCKS, 256, 0, stream>>>(deg, rowp, bsum);
    scanC_kernel<<<SCAN_BLOCKS, 256, 0, stream>>>(bsum, rowp);
    csr_fill_kernel<<<eb, 256, 0, stream>>>(ei, rowp, cursor, csr_src);
    gstart_kernel<<<(N_NODES + 255) / 256, 256, 0, stream>>>(batch, gstart);

    // ---- weights + x -> bf16 ----
    wcvt_all_kernel<<<640, 256, 0, stream>>>(Wl1, Wr1, Wl2, Wr2, Wl3, Wr3, wt1, wt2, wt3);
    cvt_kernel<<<(N_NODES * 128 / 4 + 255) / 256, 256, 0, stream>>>(
        x, hbf, N_NODES * 128 / 4);

    const int nb = (N_NODES + 7) / 8;   // 8 dsts per 256-thread block
    const int gx = NPAD / 128;          // 391, no row guards (padded workspace rows)

    // L1: K=128, FO=128 (M=256)
    gemm_bf16_kernel<<<dim3(gx, 2), 256, 0, stream>>>(hbf, wt1, hx, 128, 256);
    gat_edge_kernel<128, 4><<<nb, 256, 0, stream>>>(rowp, csr_src, hx,
                                                    att1, b1, nullptr, hbf, 1);
    // L2: K=128, FO=256 (M=512)
    gemm_bf16_kernel<<<dim3(gx, 4), 256, 0, stream>>>(hbf, wt2, hx, 128, 512);
    gat_edge_kernel<256, 8><<<nb, 256, 0, stream>>>(rowp, csr_src, hx,
                                                    att2, b2, nullptr, hbf, 1);
    // L3: K=256, FO=128 (M=256) -> h3 fp32
    gemm_bf16_kernel<<<dim3(gx, 2), 256, 0, stream>>>(hbf, wt3, hx, 256, 256);
    gat_edge_kernel<128, 4><<<nb, 256, 0, stream>>>(rowp, csr_src, hx,
                                                    att3, b3, h3, nullptr, 0);

    // pool (no atomics)
    pool2_kernel<<<N_GRAPHS, 128, 0, stream>>>(h3, gstart, gsum, gcnt);

    // MLP head
    mlp_kernel<<<N_GRAPHS, 128, 0, stream>>>(
        gsum, gcnt, Wlin1, blin1, Wlin2, blin2, Wlin3, blin3,
        bng_g, bng_b, bng_m, bng_v, bn1_g, bn1_b, bn1_m, bn1_v,
        bn2_g, bn2_b, bn2_m, bn2_v, (float*)d_out);
}